// Round 4
// baseline (892.244 us; speedup 1.0000x reference)
//
#include <hip/hip_runtime.h>

// GraphSAGE 3-layer encoder, MI355X.
// Transform-then-aggregate (mean agg is linear), CSR built per-launch.
// R3: fill_adj had 16x write amplification (105MB HBM writes for a 6.4MB adj;
// random 4B scatter -> full-line write-backs). Replaced by two-level bucketed
// fill: bucket(=256 nodes) pair scatter at 391 sequential frontiers (L2-local)
// + per-bucket LDS-cursor scatter into a ~16KB adj region.

// ---------------- CSR build ----------------

__global__ void count_deg_k(const int* __restrict__ dst, int* __restrict__ deg, int E) {
    int e = blockIdx.x * blockDim.x + threadIdx.x;
    if (e < E) atomicAdd(&deg[dst[e]], 1);
}

__global__ void scan_blocks_k(const int* __restrict__ deg, int* __restrict__ rp,
                              int* __restrict__ partials, int n) {
    __shared__ int s[256];
    int t = threadIdx.x;
    int base = blockIdx.x * 1024;
    int v[4];
    int sum = 0;
#pragma unroll
    for (int k = 0; k < 4; k++) {
        int idx = base + t * 4 + k;
        v[k] = (idx < n) ? deg[idx] : 0;
        sum += v[k];
    }
    s[t] = sum;
    __syncthreads();
    for (int off = 1; off < 256; off <<= 1) {
        int x = (t >= off) ? s[t - off] : 0;
        __syncthreads();
        s[t] += x;
        __syncthreads();
    }
    if (t == 255) partials[blockIdx.x] = s[255];
    int run = s[t] - sum;
#pragma unroll
    for (int k = 0; k < 4; k++) {
        int idx = base + t * 4 + k;
        if (idx < n) rp[idx] = run;
        run += v[k];
    }
}

__global__ void scan_partials_k(int* __restrict__ p, int nb) {
    __shared__ int s[256];
    int t = threadIdx.x;
    int v = (t < nb) ? p[t] : 0;
    s[t] = v;
    __syncthreads();
    for (int off = 1; off < 256; off <<= 1) {
        int x = (t >= off) ? s[t - off] : 0;
        __syncthreads();
        s[t] += x;
        __syncthreads();
    }
    if (t < nb) p[t] = s[t] - v;
}

// Add block offsets; set rp[n]=E; init per-bucket cursors bcur[b]=rp[b*256].
__global__ void finalize_rp_k(int* __restrict__ rp, const int* __restrict__ partials,
                              int* __restrict__ bcur, int n, int E) {
    int i = blockIdx.x * blockDim.x + threadIdx.x;
    if (i < n) {
        int v = rp[i] + partials[i >> 10];
        rp[i] = v;
        if ((i & 255) == 0) bcur[i >> 8] = v;
    }
    if (i == 0) rp[n] = E;
}

// Pass C: scatter packed (dst_local<<24 | src) into bucket-grouped pairs array.
// Frontier writes at ~391 moving cursors -> full 64B lines before eviction.
__global__ void scatter_pairs_k(const int* __restrict__ src, const int* __restrict__ dst,
                                int* __restrict__ bcur, unsigned* __restrict__ pairs, int E) {
    int e = blockIdx.x * blockDim.x + threadIdx.x;
    if (e < E) {
        int d = dst[e];
        int b = d >> 8;
        int pos = atomicAdd(&bcur[b], 1);
        pairs[pos] = ((unsigned)(d & 255) << 24) | (unsigned)src[e];
    }
}

// Pass D: one block per bucket; LDS per-node cursors; adj writes confined to
// the bucket's (~16KB, L2-resident) region.
__global__ __launch_bounds__(256) void bucket_fill_k(const int* __restrict__ rp,
                                                     const unsigned* __restrict__ pairs,
                                                     int* __restrict__ adj, int N) {
    int b = blockIdx.x;
    int t = threadIdx.x;
    int node0 = b << 8;
    int nEnd = min(node0 + 256, N);
    __shared__ int base[256];
    __shared__ int cur[256];
    if (node0 + t < nEnd) base[t] = rp[node0 + t];
    cur[t] = 0;
    __syncthreads();
    int e0 = rp[node0];
    int e1 = rp[nEnd];
    for (int e = e0 + t; e < e1; e += 256) {
        unsigned p = pairs[e];
        int local = p >> 24;
        int s = (int)(p & 0xFFFFFFu);
        int pos = base[local] + atomicAdd(&cur[local], 1);
        adj[pos] = s;
    }
}

// ---------------- tiled dual GEMM: Y = H @ Wl^T ; Z = H @ Wr^T + b ----------------

template <int DOUT>
__global__ __launch_bounds__(256, 2) void gemm_tile_k(const float* __restrict__ H,
                                                      const float* __restrict__ Wl,
                                                      const float* __restrict__ Wr,
                                                      const float* __restrict__ b,
                                                      float* __restrict__ Y,
                                                      float* __restrict__ Z, int N) {
    constexpr int DOUT2 = 2 * DOUT;   // 128 or 64
    constexpr int CPT = DOUT2 / 16;   // cols/thread: 8 or 4
    constexpr int ST = 68;            // padded LDS stride (floats)
    __shared__ float hs[64 * ST];
    __shared__ float ws[DOUT2 * ST];
    int t = threadIdx.x;

    for (int i = t; i < DOUT2 * 16; i += 256) {
        int c = i >> 4, j4 = i & 15;
        float4 w = (c < DOUT) ? reinterpret_cast<const float4*>(Wl)[c * 16 + j4]
                              : reinterpret_cast<const float4*>(Wr)[(c - DOUT) * 16 + j4];
        *reinterpret_cast<float4*>(&ws[c * ST + j4 * 4]) = w;
    }
    {
        const float4* H4 = reinterpret_cast<const float4*>(H);
        long base4 = (long)blockIdx.x * 64 * 16;
        long max4 = (long)N * 16 - 1;
        for (int i = t; i < 64 * 16; i += 256) {
            long g = base4 + i;
            if (g > max4) g = max4;
            float4 h = H4[g];
            int row = i >> 4, j4 = i & 15;
            *reinterpret_cast<float4*>(&hs[row * ST + j4 * 4]) = h;
        }
    }
    __syncthreads();

    int tx = t & 15;
    int ty = t >> 4;
    float acc[4][CPT];
#pragma unroll
    for (int r = 0; r < 4; r++)
#pragma unroll
        for (int c = 0; c < CPT; c++) acc[r][c] = 0.f;

#pragma unroll 2
    for (int k4 = 0; k4 < 16; ++k4) {
        float4 a[4], w[CPT];
#pragma unroll
        for (int r = 0; r < 4; r++)
            a[r] = *reinterpret_cast<const float4*>(&hs[(ty * 4 + r) * ST + k4 * 4]);
#pragma unroll
        for (int c = 0; c < CPT; c++)
            w[c] = *reinterpret_cast<const float4*>(&ws[(tx + 16 * c) * ST + k4 * 4]);
#pragma unroll
        for (int r = 0; r < 4; r++)
#pragma unroll
            for (int c = 0; c < CPT; c++)
                acc[r][c] = fmaf(a[r].x, w[c].x,
                            fmaf(a[r].y, w[c].y,
                            fmaf(a[r].z, w[c].z, fmaf(a[r].w, w[c].w, acc[r][c]))));
    }

    int row0 = blockIdx.x * 64 + ty * 4;
#pragma unroll
    for (int r = 0; r < 4; r++) {
        int row = row0 + r;
        if (row >= N) break;
#pragma unroll
        for (int c = 0; c < CPT; c++) {
            int col = tx + 16 * c;
            if (col < DOUT)
                Y[row * DOUT + col] = acc[r][c];
            else
                Z[row * DOUT + (col - DOUT)] = acc[r][c] + b[col - DOUT];
        }
    }
}

// ---------------- aggregate: H[i] += mean_{e in adj(i)} Y[adj[e]] ; opt ReLU ----------------

template <int DOUT, bool RELU>
__global__ __launch_bounds__(256) void aggregate_k(const int* __restrict__ rp,
                                                   const int* __restrict__ adj,
                                                   const float* __restrict__ Y,
                                                   float* __restrict__ H, int N) {
    constexpr int FPR = DOUT / 4;        // float4 lanes per row: 16 or 8
    constexpr int NSLOT = 64 / FPR;      // edge slots: 4 or 8
    int wave = threadIdx.x >> 6;
    int lane = threadIdx.x & 63;
    int slot = lane / FPR;
    int d4 = lane % FPR;
    int node = blockIdx.x * 4 + wave;
    if (node >= N) return;
    int s0 = rp[node], s1 = rp[node + 1];
    const float4* Y4 = reinterpret_cast<const float4*>(Y);
    float4 acc = make_float4(0.f, 0.f, 0.f, 0.f);
    int e = s0 + slot;
    for (; e + NSLOT < s1; e += 2 * NSLOT) {
        int a0 = adj[e], a1 = adj[e + NSLOT];
        float4 y0 = Y4[(long)a0 * FPR + d4];
        float4 y1 = Y4[(long)a1 * FPR + d4];
        acc.x += y0.x; acc.y += y0.y; acc.z += y0.z; acc.w += y0.w;
        acc.x += y1.x; acc.y += y1.y; acc.z += y1.z; acc.w += y1.w;
    }
    if (e < s1) {
        float4 y0 = Y4[(long)adj[e] * FPR + d4];
        acc.x += y0.x; acc.y += y0.y; acc.z += y0.z; acc.w += y0.w;
    }
#pragma unroll
    for (int m = FPR; m < 64; m <<= 1) {
        acc.x += __shfl_xor(acc.x, m);
        acc.y += __shfl_xor(acc.y, m);
        acc.z += __shfl_xor(acc.z, m);
        acc.w += __shfl_xor(acc.w, m);
    }
    int deg = s1 - s0;
    if (lane < FPR) {
        float4* H4 = reinterpret_cast<float4*>(H);
        float4 v = H4[(long)node * FPR + d4];
        if (deg > 0) {
            float inv = 1.f / (float)deg;
            v.x += acc.x * inv; v.y += acc.y * inv;
            v.z += acc.z * inv; v.w += acc.w * inv;
        }
        if (RELU) {
            v.x = fmaxf(v.x, 0.f); v.y = fmaxf(v.y, 0.f);
            v.z = fmaxf(v.z, 0.f); v.w = fmaxf(v.w, 0.f);
        }
        H4[(long)node * FPR + d4] = v;
    }
}

// ---------------- launch ----------------

extern "C" void kernel_launch(void* const* d_in, const int* in_sizes, int n_in,
                              void* d_out, int out_size, void* d_ws, size_t ws_size,
                              hipStream_t stream) {
    const float* x = (const float*)d_in[0];
    const int* ei = (const int*)d_in[1];  // int32
    const float* Wl0 = (const float*)d_in[3];
    const float* Wr0 = (const float*)d_in[4];
    const float* b0 = (const float*)d_in[5];
    const float* Wl1 = (const float*)d_in[6];
    const float* Wr1 = (const float*)d_in[7];
    const float* b1 = (const float*)d_in[8];
    const float* Wl2 = (const float*)d_in[9];
    const float* Wr2 = (const float*)d_in[10];
    const float* b2 = (const float*)d_in[11];

    int N = in_sizes[0] / 64;
    int E = in_sizes[1] / 2;
    const int* src = ei;
    const int* dstp = ei + E;

    char* ws = (char*)d_ws;
    size_t off = 0;
    auto take = [&](size_t bytes) -> void* {
        void* p = ws + off;
        off = (off + bytes + 255) & ~(size_t)255;
        return p;
    };
    int* rowptr = (int*)take((size_t)(N + 1) * 4);
    int* deg = (int*)take((size_t)N * 4);
    int* partials = (int*)take(4096);
    int* bcur = (int*)take(8192);
    int* adj = (int*)take((size_t)E * 4);
    float* Y = (float*)take((size_t)N * 64 * 4);
    float* HA = (float*)take((size_t)N * 64 * 4);
    float* HB = (float*)take((size_t)N * 64 * 4);
    (void)ws_size;
    (void)n_in;
    (void)out_size;

    // pairs buffer aliases Y: CSR build fully precedes gemm0's writes to Y
    // (same stream), and E*4 (6.4MB) <= N*64*4 (25.6MB).
    unsigned* pairs = (unsigned*)Y;

    int nbuckets = (N + 255) / 256;

    // CSR build
    hipMemsetAsync(deg, 0, (size_t)N * 4, stream);
    count_deg_k<<<(E + 255) / 256, 256, 0, stream>>>(dstp, deg, E);
    int nb = (N + 1023) / 1024;
    scan_blocks_k<<<nb, 256, 0, stream>>>(deg, rowptr, partials, N);
    scan_partials_k<<<1, 256, 0, stream>>>(partials, nb);
    finalize_rp_k<<<(N + 255) / 256, 256, 0, stream>>>(rowptr, partials, bcur, N, E);
    scatter_pairs_k<<<(E + 255) / 256, 256, 0, stream>>>(src, dstp, bcur, pairs, E);
    bucket_fill_k<<<nbuckets, 256, 0, stream>>>(rowptr, pairs, adj, N);

    float* out = (float*)d_out;
    int gb = (N + 63) / 64;
    int ab = (N + 3) / 4;

    // layer 0: x -> HA (relu)
    gemm_tile_k<64><<<gb, 256, 0, stream>>>(x, Wl0, Wr0, b0, Y, HA, N);
    aggregate_k<64, true><<<ab, 256, 0, stream>>>(rowptr, adj, Y, HA, N);
    // layer 1: HA -> HB (relu)
    gemm_tile_k<64><<<gb, 256, 0, stream>>>(HA, Wl1, Wr1, b1, Y, HB, N);
    aggregate_k<64, true><<<ab, 256, 0, stream>>>(rowptr, adj, Y, HB, N);
    // layer 2: HB -> out (no relu)
    gemm_tile_k<32><<<gb, 256, 0, stream>>>(HB, Wl2, Wr2, b2, Y, out, N);
    aggregate_k<32, false><<<ab, 256, 0, stream>>>(rowptr, adj, Y, out, N);
}

// Round 5
// 292.230 us; speedup vs baseline: 3.0532x; 3.0532x over previous
//
#include <hip/hip_runtime.h>

// GraphSAGE 3-layer encoder, MI355X.
// Transform-then-aggregate (mean agg is linear), CSR built per-launch.
// R4: R3's 391 global bucket cursors serialized (136ns/same-address atomic,
// 557us). Replaced with atomic-free radix partition: per-block LDS histogram
// -> two-level scan -> private-range scatter; per-bucket fill also computes
// rowptr (no global atomics anywhere in CSR build).

#define MAXB 512   // max node buckets (bucket = 256 nodes); N <= 131072
#define NBLK 256   // partition blocks

// ---- pass 1: per-block histogram over dst buckets ----
__global__ __launch_bounds__(256) void hist_k(const int* __restrict__ dst, int E,
                                              int nb, int* __restrict__ ghist) {
    __shared__ int h[MAXB];
    for (int i = threadIdx.x; i < nb; i += 256) h[i] = 0;
    __syncthreads();
    int chunk = (E + NBLK - 1) / NBLK;
    int e0 = blockIdx.x * chunk, e1 = min(e0 + chunk, E);
    for (int e = e0 + threadIdx.x; e < e1; e += 256) atomicAdd(&h[dst[e] >> 8], 1);
    __syncthreads();
    for (int i = threadIdx.x; i < nb; i += 256) ghist[blockIdx.x * MAXB + i] = h[i];
}

// ---- pass 2a: per-bucket exclusive scan over block counts (in place) ----
__global__ __launch_bounds__(256) void col_scan_k(int* __restrict__ ghist,
                                                  int* __restrict__ colsum) {
    int bucket = blockIdx.x;
    int t = threadIdx.x;
    __shared__ int s[256];
    int v = ghist[t * MAXB + bucket];
    s[t] = v;
    __syncthreads();
    for (int off = 1; off < 256; off <<= 1) {
        int x = (t >= off) ? s[t - off] : 0;
        __syncthreads();
        s[t] += x;
        __syncthreads();
    }
    ghist[t * MAXB + bucket] = s[t] - v;  // exclusive prefix for this block
    if (t == 255) colsum[bucket] = s[255];
}

// ---- pass 2b: exclusive scan of bucket totals ----
__global__ __launch_bounds__(512) void bucket_scan_k(const int* __restrict__ colsum,
                                                     int* __restrict__ bbase, int nb) {
    __shared__ int s[512];
    int t = threadIdx.x;
    int v = (t < nb) ? colsum[t] : 0;
    s[t] = v;
    __syncthreads();
    for (int off = 1; off < 512; off <<= 1) {
        int x = (t >= off) ? s[t - off] : 0;
        __syncthreads();
        s[t] += x;
        __syncthreads();
    }
    if (t < nb) bbase[t] = s[t] - v;
}

// ---- pass 3: scatter edges into private contiguous sub-ranges ----
__global__ __launch_bounds__(256) void partition_k(const int* __restrict__ src,
                                                   const int* __restrict__ dst,
                                                   const int* __restrict__ ghist,
                                                   const int* __restrict__ bbase,
                                                   unsigned* __restrict__ pairs,
                                                   int E, int nb) {
    __shared__ int cur[MAXB];
    for (int i = threadIdx.x; i < nb; i += 256)
        cur[i] = bbase[i] + ghist[blockIdx.x * MAXB + i];
    __syncthreads();
    int chunk = (E + NBLK - 1) / NBLK;
    int e0 = blockIdx.x * chunk, e1 = min(e0 + chunk, E);
    for (int e = e0 + threadIdx.x; e < e1; e += 256) {
        int d = dst[e];
        int b = d >> 8;
        int pos = atomicAdd(&cur[b], 1);               // LDS atomic only
        pairs[pos] = ((unsigned)(d & 255) << 24) | (unsigned)src[e];
    }
}

// ---- pass 4: per-bucket local-deg count + scan -> rowptr; scatter adj ----
__global__ __launch_bounds__(256) void bucket_fill2_k(const unsigned* __restrict__ pairs,
                                                      const int* __restrict__ bbase,
                                                      const int* __restrict__ colsum,
                                                      int* __restrict__ rowptr,
                                                      int* __restrict__ adj,
                                                      int N, int E) {
    int b = blockIdx.x, t = threadIdx.x;
    int node0 = b << 8;
    int nloc = min(256, N - node0);
    int e0 = bbase[b];
    int e1 = e0 + colsum[b];
    __shared__ int cnt[256];
    __shared__ int s[256];
    __shared__ int base[256];
    cnt[t] = 0;
    __syncthreads();
    for (int e = e0 + t; e < e1; e += 256) atomicAdd(&cnt[pairs[e] >> 24], 1);
    __syncthreads();
    int v = cnt[t];
    s[t] = v;
    __syncthreads();
    for (int off = 1; off < 256; off <<= 1) {
        int x = (t >= off) ? s[t - off] : 0;
        __syncthreads();
        s[t] += x;
        __syncthreads();
    }
    base[t] = e0 + s[t] - v;  // exclusive
    if (t < nloc) rowptr[node0 + t] = base[t];
    if (b == 0 && t == 0) rowptr[N] = E;
    cnt[t] = 0;
    __syncthreads();
    for (int e = e0 + t; e < e1; e += 256) {
        unsigned p = pairs[e];
        int l = p >> 24;
        int pos = base[l] + atomicAdd(&cnt[l], 1);     // LDS atomic only
        adj[pos] = (int)(p & 0xFFFFFFu);
    }
}

// ---------------- tiled dual GEMM: Y = H @ Wl^T ; Z = H @ Wr^T + b ----------------

template <int DOUT>
__global__ __launch_bounds__(256, 2) void gemm_tile_k(const float* __restrict__ H,
                                                      const float* __restrict__ Wl,
                                                      const float* __restrict__ Wr,
                                                      const float* __restrict__ b,
                                                      float* __restrict__ Y,
                                                      float* __restrict__ Z, int N) {
    constexpr int DOUT2 = 2 * DOUT;   // 128 or 64
    constexpr int CPT = DOUT2 / 16;   // cols/thread: 8 or 4
    constexpr int ST = 68;            // padded LDS stride (floats)
    __shared__ float hs[64 * ST];
    __shared__ float ws[DOUT2 * ST];
    int t = threadIdx.x;

    for (int i = t; i < DOUT2 * 16; i += 256) {
        int c = i >> 4, j4 = i & 15;
        float4 w = (c < DOUT) ? reinterpret_cast<const float4*>(Wl)[c * 16 + j4]
                              : reinterpret_cast<const float4*>(Wr)[(c - DOUT) * 16 + j4];
        *reinterpret_cast<float4*>(&ws[c * ST + j4 * 4]) = w;
    }
    {
        const float4* H4 = reinterpret_cast<const float4*>(H);
        long base4 = (long)blockIdx.x * 64 * 16;
        long max4 = (long)N * 16 - 1;
        for (int i = t; i < 64 * 16; i += 256) {
            long g = base4 + i;
            if (g > max4) g = max4;
            float4 h = H4[g];
            int row = i >> 4, j4 = i & 15;
            *reinterpret_cast<float4*>(&hs[row * ST + j4 * 4]) = h;
        }
    }
    __syncthreads();

    int tx = t & 15;
    int ty = t >> 4;
    float acc[4][CPT];
#pragma unroll
    for (int r = 0; r < 4; r++)
#pragma unroll
        for (int c = 0; c < CPT; c++) acc[r][c] = 0.f;

#pragma unroll 2
    for (int k4 = 0; k4 < 16; ++k4) {
        float4 a[4], w[CPT];
#pragma unroll
        for (int r = 0; r < 4; r++)
            a[r] = *reinterpret_cast<const float4*>(&hs[(ty * 4 + r) * ST + k4 * 4]);
#pragma unroll
        for (int c = 0; c < CPT; c++)
            w[c] = *reinterpret_cast<const float4*>(&ws[(tx + 16 * c) * ST + k4 * 4]);
#pragma unroll
        for (int r = 0; r < 4; r++)
#pragma unroll
            for (int c = 0; c < CPT; c++)
                acc[r][c] = fmaf(a[r].x, w[c].x,
                            fmaf(a[r].y, w[c].y,
                            fmaf(a[r].z, w[c].z, fmaf(a[r].w, w[c].w, acc[r][c]))));
    }

    int row0 = blockIdx.x * 64 + ty * 4;
#pragma unroll
    for (int r = 0; r < 4; r++) {
        int row = row0 + r;
        if (row >= N) break;
#pragma unroll
        for (int c = 0; c < CPT; c++) {
            int col = tx + 16 * c;
            if (col < DOUT)
                Y[row * DOUT + col] = acc[r][c];
            else
                Z[row * DOUT + (col - DOUT)] = acc[r][c] + b[col - DOUT];
        }
    }
}

// ---------------- aggregate: H[i] += mean_{e in adj(i)} Y[adj[e]] ; opt ReLU ----------------

template <int DOUT, bool RELU>
__global__ __launch_bounds__(256) void aggregate_k(const int* __restrict__ rp,
                                                   const int* __restrict__ adj,
                                                   const float* __restrict__ Y,
                                                   float* __restrict__ H, int N) {
    constexpr int FPR = DOUT / 4;        // float4 lanes per row: 16 or 8
    constexpr int NSLOT = 64 / FPR;      // edge slots: 4 or 8
    int wave = threadIdx.x >> 6;
    int lane = threadIdx.x & 63;
    int slot = lane / FPR;
    int d4 = lane % FPR;
    int node = blockIdx.x * 4 + wave;
    if (node >= N) return;
    int s0 = rp[node], s1 = rp[node + 1];
    const float4* Y4 = reinterpret_cast<const float4*>(Y);
    float4 acc = make_float4(0.f, 0.f, 0.f, 0.f);
    int e = s0 + slot;
    for (; e + NSLOT < s1; e += 2 * NSLOT) {
        int a0 = adj[e], a1 = adj[e + NSLOT];
        float4 y0 = Y4[(long)a0 * FPR + d4];
        float4 y1 = Y4[(long)a1 * FPR + d4];
        acc.x += y0.x; acc.y += y0.y; acc.z += y0.z; acc.w += y0.w;
        acc.x += y1.x; acc.y += y1.y; acc.z += y1.z; acc.w += y1.w;
    }
    if (e < s1) {
        float4 y0 = Y4[(long)adj[e] * FPR + d4];
        acc.x += y0.x; acc.y += y0.y; acc.z += y0.z; acc.w += y0.w;
    }
#pragma unroll
    for (int m = FPR; m < 64; m <<= 1) {
        acc.x += __shfl_xor(acc.x, m);
        acc.y += __shfl_xor(acc.y, m);
        acc.z += __shfl_xor(acc.z, m);
        acc.w += __shfl_xor(acc.w, m);
    }
    int deg = s1 - s0;
    if (lane < FPR) {
        float4* H4 = reinterpret_cast<float4*>(H);
        float4 v = H4[(long)node * FPR + d4];
        if (deg > 0) {
            float inv = 1.f / (float)deg;
            v.x += acc.x * inv; v.y += acc.y * inv;
            v.z += acc.z * inv; v.w += acc.w * inv;
        }
        if (RELU) {
            v.x = fmaxf(v.x, 0.f); v.y = fmaxf(v.y, 0.f);
            v.z = fmaxf(v.z, 0.f); v.w = fmaxf(v.w, 0.f);
        }
        H4[(long)node * FPR + d4] = v;
    }
}

// ---------------- launch ----------------

extern "C" void kernel_launch(void* const* d_in, const int* in_sizes, int n_in,
                              void* d_out, int out_size, void* d_ws, size_t ws_size,
                              hipStream_t stream) {
    const float* x = (const float*)d_in[0];
    const int* ei = (const int*)d_in[1];  // int32
    const float* Wl0 = (const float*)d_in[3];
    const float* Wr0 = (const float*)d_in[4];
    const float* b0 = (const float*)d_in[5];
    const float* Wl1 = (const float*)d_in[6];
    const float* Wr1 = (const float*)d_in[7];
    const float* b1 = (const float*)d_in[8];
    const float* Wl2 = (const float*)d_in[9];
    const float* Wr2 = (const float*)d_in[10];
    const float* b2 = (const float*)d_in[11];

    int N = in_sizes[0] / 64;
    int E = in_sizes[1] / 2;
    const int* src = ei;
    const int* dstp = ei + E;

    char* ws = (char*)d_ws;
    size_t off = 0;
    auto take = [&](size_t bytes) -> void* {
        void* p = ws + off;
        off = (off + bytes + 255) & ~(size_t)255;
        return p;
    };
    int* rowptr = (int*)take((size_t)(N + 1) * 4);
    int* ghist = (int*)take((size_t)NBLK * MAXB * 4);
    int* colsum = (int*)take(MAXB * 4);
    int* bbase = (int*)take(MAXB * 4);
    int* adj = (int*)take((size_t)E * 4);
    float* Y = (float*)take((size_t)N * 64 * 4);
    float* HA = (float*)take((size_t)N * 64 * 4);
    float* HB = (float*)take((size_t)N * 64 * 4);
    (void)ws_size;
    (void)n_in;
    (void)out_size;

    // pairs buffer aliases Y: CSR build fully precedes gemm0's writes to Y.
    unsigned* pairs = (unsigned*)Y;

    int nb = (N + 255) / 256;

    // CSR build (no global atomics)
    hist_k<<<NBLK, 256, 0, stream>>>(dstp, E, nb, ghist);
    col_scan_k<<<nb, 256, 0, stream>>>(ghist, colsum);
    bucket_scan_k<<<1, 512, 0, stream>>>(colsum, bbase, nb);
    partition_k<<<NBLK, 256, 0, stream>>>(src, dstp, ghist, bbase, pairs, E, nb);
    bucket_fill2_k<<<nb, 256, 0, stream>>>(pairs, bbase, colsum, rowptr, adj, N, E);

    float* out = (float*)d_out;
    int gb = (N + 63) / 64;
    int ab = (N + 3) / 4;

    // layer 0: x -> HA (relu)
    gemm_tile_k<64><<<gb, 256, 0, stream>>>(x, Wl0, Wr0, b0, Y, HA, N);
    aggregate_k<64, true><<<ab, 256, 0, stream>>>(rowptr, adj, Y, HA, N);
    // layer 1: HA -> HB (relu)
    gemm_tile_k<64><<<gb, 256, 0, stream>>>(HA, Wl1, Wr1, b1, Y, HB, N);
    aggregate_k<64, true><<<ab, 256, 0, stream>>>(rowptr, adj, Y, HB, N);
    // layer 2: HB -> out (no relu)
    gemm_tile_k<32><<<gb, 256, 0, stream>>>(HB, Wl2, Wr2, b2, Y, out, N);
    aggregate_k<32, false><<<ab, 256, 0, stream>>>(rowptr, adj, Y, out, N);
}

// Round 6
// 257.108 us; speedup vs baseline: 3.4703x; 1.1366x over previous
//
#include <hip/hip_runtime.h>
#include <hip/hip_fp16.h>

// GraphSAGE 3-layer encoder, MI355X.
// Transform-then-aggregate (mean agg is linear), CSR built per-launch
// (atomic-free radix partition, R4). R5: Y (gather operand, only consumed by
// aggregate) stored fp16 -> halves gather bytes AND gather instructions.
// fp32 accumulation; H/Z stay fp32.

#define MAXB 512   // max node buckets (bucket = 256 nodes); N <= 131072
#define NBLK 256   // partition blocks

// ---- pass 1: per-block histogram over dst buckets ----
__global__ __launch_bounds__(256) void hist_k(const int* __restrict__ dst, int E,
                                              int nb, int* __restrict__ ghist) {
    __shared__ int h[MAXB];
    for (int i = threadIdx.x; i < nb; i += 256) h[i] = 0;
    __syncthreads();
    int chunk = (E + NBLK - 1) / NBLK;
    int e0 = blockIdx.x * chunk, e1 = min(e0 + chunk, E);
    for (int e = e0 + threadIdx.x; e < e1; e += 256) atomicAdd(&h[dst[e] >> 8], 1);
    __syncthreads();
    for (int i = threadIdx.x; i < nb; i += 256) ghist[blockIdx.x * MAXB + i] = h[i];
}

// ---- pass 2a: per-bucket exclusive scan over block counts (in place) ----
__global__ __launch_bounds__(256) void col_scan_k(int* __restrict__ ghist,
                                                  int* __restrict__ colsum) {
    int bucket = blockIdx.x;
    int t = threadIdx.x;
    __shared__ int s[256];
    int v = ghist[t * MAXB + bucket];
    s[t] = v;
    __syncthreads();
    for (int off = 1; off < 256; off <<= 1) {
        int x = (t >= off) ? s[t - off] : 0;
        __syncthreads();
        s[t] += x;
        __syncthreads();
    }
    ghist[t * MAXB + bucket] = s[t] - v;  // exclusive prefix for this block
    if (t == 255) colsum[bucket] = s[255];
}

// ---- pass 2b: exclusive scan of bucket totals ----
__global__ __launch_bounds__(512) void bucket_scan_k(const int* __restrict__ colsum,
                                                     int* __restrict__ bbase, int nb) {
    __shared__ int s[512];
    int t = threadIdx.x;
    int v = (t < nb) ? colsum[t] : 0;
    s[t] = v;
    __syncthreads();
    for (int off = 1; off < 512; off <<= 1) {
        int x = (t >= off) ? s[t - off] : 0;
        __syncthreads();
        s[t] += x;
        __syncthreads();
    }
    if (t < nb) bbase[t] = s[t] - v;
}

// ---- pass 3: scatter edges into private contiguous sub-ranges ----
__global__ __launch_bounds__(256) void partition_k(const int* __restrict__ src,
                                                   const int* __restrict__ dst,
                                                   const int* __restrict__ ghist,
                                                   const int* __restrict__ bbase,
                                                   unsigned* __restrict__ pairs,
                                                   int E, int nb) {
    __shared__ int cur[MAXB];
    for (int i = threadIdx.x; i < nb; i += 256)
        cur[i] = bbase[i] + ghist[blockIdx.x * MAXB + i];
    __syncthreads();
    int chunk = (E + NBLK - 1) / NBLK;
    int e0 = blockIdx.x * chunk, e1 = min(e0 + chunk, E);
    for (int e = e0 + threadIdx.x; e < e1; e += 256) {
        int d = dst[e];
        int b = d >> 8;
        int pos = atomicAdd(&cur[b], 1);               // LDS atomic only
        pairs[pos] = ((unsigned)(d & 255) << 24) | (unsigned)src[e];
    }
}

// ---- pass 4: per-bucket local-deg count + scan -> rowptr; scatter adj ----
__global__ __launch_bounds__(256) void bucket_fill2_k(const unsigned* __restrict__ pairs,
                                                      const int* __restrict__ bbase,
                                                      const int* __restrict__ colsum,
                                                      int* __restrict__ rowptr,
                                                      int* __restrict__ adj,
                                                      int N, int E) {
    int b = blockIdx.x, t = threadIdx.x;
    int node0 = b << 8;
    int nloc = min(256, N - node0);
    int e0 = bbase[b];
    int e1 = e0 + colsum[b];
    __shared__ int cnt[256];
    __shared__ int s[256];
    __shared__ int base[256];
    cnt[t] = 0;
    __syncthreads();
    for (int e = e0 + t; e < e1; e += 256) atomicAdd(&cnt[pairs[e] >> 24], 1);
    __syncthreads();
    int v = cnt[t];
    s[t] = v;
    __syncthreads();
    for (int off = 1; off < 256; off <<= 1) {
        int x = (t >= off) ? s[t - off] : 0;
        __syncthreads();
        s[t] += x;
        __syncthreads();
    }
    base[t] = e0 + s[t] - v;  // exclusive
    if (t < nloc) rowptr[node0 + t] = base[t];
    if (b == 0 && t == 0) rowptr[N] = E;
    cnt[t] = 0;
    __syncthreads();
    for (int e = e0 + t; e < e1; e += 256) {
        unsigned p = pairs[e];
        int l = p >> 24;
        int pos = base[l] + atomicAdd(&cnt[l], 1);     // LDS atomic only
        adj[pos] = (int)(p & 0xFFFFFFu);
    }
}

// ---------------- tiled dual GEMM: Y(fp16) = H @ Wl^T ; Z(fp32) = H @ Wr^T + b ----------------

template <int DOUT>
__global__ __launch_bounds__(256, 2) void gemm_tile_k(const float* __restrict__ H,
                                                      const float* __restrict__ Wl,
                                                      const float* __restrict__ Wr,
                                                      const float* __restrict__ b,
                                                      __half* __restrict__ Y,
                                                      float* __restrict__ Z, int N) {
    constexpr int DOUT2 = 2 * DOUT;   // 128 or 64
    constexpr int CPT = DOUT2 / 16;   // cols/thread: 8 or 4
    constexpr int ST = 68;            // padded LDS stride (floats)
    __shared__ float hs[64 * ST];
    __shared__ float ws[DOUT2 * ST];
    int t = threadIdx.x;

    for (int i = t; i < DOUT2 * 16; i += 256) {
        int c = i >> 4, j4 = i & 15;
        float4 w = (c < DOUT) ? reinterpret_cast<const float4*>(Wl)[c * 16 + j4]
                              : reinterpret_cast<const float4*>(Wr)[(c - DOUT) * 16 + j4];
        *reinterpret_cast<float4*>(&ws[c * ST + j4 * 4]) = w;
    }
    {
        const float4* H4 = reinterpret_cast<const float4*>(H);
        long base4 = (long)blockIdx.x * 64 * 16;
        long max4 = (long)N * 16 - 1;
        for (int i = t; i < 64 * 16; i += 256) {
            long g = base4 + i;
            if (g > max4) g = max4;
            float4 h = H4[g];
            int row = i >> 4, j4 = i & 15;
            *reinterpret_cast<float4*>(&hs[row * ST + j4 * 4]) = h;
        }
    }
    __syncthreads();

    int tx = t & 15;
    int ty = t >> 4;
    float acc[4][CPT];
#pragma unroll
    for (int r = 0; r < 4; r++)
#pragma unroll
        for (int c = 0; c < CPT; c++) acc[r][c] = 0.f;

#pragma unroll 2
    for (int k4 = 0; k4 < 16; ++k4) {
        float4 a[4], w[CPT];
#pragma unroll
        for (int r = 0; r < 4; r++)
            a[r] = *reinterpret_cast<const float4*>(&hs[(ty * 4 + r) * ST + k4 * 4]);
#pragma unroll
        for (int c = 0; c < CPT; c++)
            w[c] = *reinterpret_cast<const float4*>(&ws[(tx + 16 * c) * ST + k4 * 4]);
#pragma unroll
        for (int r = 0; r < 4; r++)
#pragma unroll
            for (int c = 0; c < CPT; c++)
                acc[r][c] = fmaf(a[r].x, w[c].x,
                            fmaf(a[r].y, w[c].y,
                            fmaf(a[r].z, w[c].z, fmaf(a[r].w, w[c].w, acc[r][c]))));
    }

    int row0 = blockIdx.x * 64 + ty * 4;
#pragma unroll
    for (int r = 0; r < 4; r++) {
        int row = row0 + r;
        if (row >= N) break;
#pragma unroll
        for (int c = 0; c < CPT; c++) {
            int col = tx + 16 * c;
            if (col < DOUT)
                Y[(long)row * DOUT + col] = __float2half(acc[r][c]);
            else
                Z[(long)row * DOUT + (col - DOUT)] = acc[r][c] + b[col - DOUT];
        }
    }
}

// ---------------- aggregate: H[i] += mean_{e in adj(i)} Y[adj[e]] ; opt ReLU ----------------
// Y is fp16. Each lane loads 16B = 8 halves; FPR lanes per row; NSLOT edge slots.

template <int DOUT, bool RELU>
__global__ __launch_bounds__(256) void aggregate_k(const int* __restrict__ rp,
                                                   const int* __restrict__ adj,
                                                   const __half* __restrict__ Yh,
                                                   float* __restrict__ H, int N) {
    constexpr int FPR = DOUT / 8;        // 16B-lane-loads per row: 8 (d64) or 4 (d32)
    constexpr int NSLOT = 64 / FPR;      // edge slots: 8 or 16
    int wave = threadIdx.x >> 6;
    int lane = threadIdx.x & 63;
    int slot = lane / FPR;
    int d8 = lane % FPR;
    int node = blockIdx.x * 4 + wave;
    if (node >= N) return;
    int s0 = rp[node], s1 = rp[node + 1];
    const float4* Y4 = reinterpret_cast<const float4*>(Yh);
    float acc[8];
#pragma unroll
    for (int k = 0; k < 8; k++) acc[k] = 0.f;

    int e = s0 + slot;
    for (; e + NSLOT < s1; e += 2 * NSLOT) {
        int a0 = adj[e], a1 = adj[e + NSLOT];
        float4 r0 = Y4[(long)a0 * FPR + d8];
        float4 r1 = Y4[(long)a1 * FPR + d8];
        const __half2* h0 = reinterpret_cast<const __half2*>(&r0);
        const __half2* h1 = reinterpret_cast<const __half2*>(&r1);
#pragma unroll
        for (int k = 0; k < 4; k++) {
            float2 f0 = __half22float2(h0[k]);
            float2 f1 = __half22float2(h1[k]);
            acc[2 * k] += f0.x + f1.x;
            acc[2 * k + 1] += f0.y + f1.y;
        }
    }
    if (e < s1) {
        float4 r0 = Y4[(long)adj[e] * FPR + d8];
        const __half2* h0 = reinterpret_cast<const __half2*>(&r0);
#pragma unroll
        for (int k = 0; k < 4; k++) {
            float2 f0 = __half22float2(h0[k]);
            acc[2 * k] += f0.x;
            acc[2 * k + 1] += f0.y;
        }
    }
    // cross-slot reduce: lanes differing in slot bits (>= FPR)
#pragma unroll
    for (int m = FPR; m < 64; m <<= 1) {
#pragma unroll
        for (int k = 0; k < 8; k++) acc[k] += __shfl_xor(acc[k], m);
    }
    int deg = s1 - s0;
    if (lane < FPR) {
        float4* H4 = reinterpret_cast<float4*>(H);
        long hb = (long)node * (DOUT / 4) + d8 * 2;  // lane owns 8 consecutive dims
        float4 v0 = H4[hb], v1 = H4[hb + 1];
        if (deg > 0) {
            float inv = 1.f / (float)deg;
            v0.x += acc[0] * inv; v0.y += acc[1] * inv;
            v0.z += acc[2] * inv; v0.w += acc[3] * inv;
            v1.x += acc[4] * inv; v1.y += acc[5] * inv;
            v1.z += acc[6] * inv; v1.w += acc[7] * inv;
        }
        if (RELU) {
            v0.x = fmaxf(v0.x, 0.f); v0.y = fmaxf(v0.y, 0.f);
            v0.z = fmaxf(v0.z, 0.f); v0.w = fmaxf(v0.w, 0.f);
            v1.x = fmaxf(v1.x, 0.f); v1.y = fmaxf(v1.y, 0.f);
            v1.z = fmaxf(v1.z, 0.f); v1.w = fmaxf(v1.w, 0.f);
        }
        H4[hb] = v0;
        H4[hb + 1] = v1;
    }
}

// ---------------- launch ----------------

extern "C" void kernel_launch(void* const* d_in, const int* in_sizes, int n_in,
                              void* d_out, int out_size, void* d_ws, size_t ws_size,
                              hipStream_t stream) {
    const float* x = (const float*)d_in[0];
    const int* ei = (const int*)d_in[1];  // int32
    const float* Wl0 = (const float*)d_in[3];
    const float* Wr0 = (const float*)d_in[4];
    const float* b0 = (const float*)d_in[5];
    const float* Wl1 = (const float*)d_in[6];
    const float* Wr1 = (const float*)d_in[7];
    const float* b1 = (const float*)d_in[8];
    const float* Wl2 = (const float*)d_in[9];
    const float* Wr2 = (const float*)d_in[10];
    const float* b2 = (const float*)d_in[11];

    int N = in_sizes[0] / 64;
    int E = in_sizes[1] / 2;
    const int* src = ei;
    const int* dstp = ei + E;

    char* ws = (char*)d_ws;
    size_t off = 0;
    auto take = [&](size_t bytes) -> void* {
        void* p = ws + off;
        off = (off + bytes + 255) & ~(size_t)255;
        return p;
    };
    int* rowptr = (int*)take((size_t)(N + 1) * 4);
    int* ghist = (int*)take((size_t)NBLK * MAXB * 4);
    int* colsum = (int*)take(MAXB * 4);
    int* bbase = (int*)take(MAXB * 4);
    int* adj = (int*)take((size_t)E * 4);
    __half* Yh = (__half*)take((size_t)N * 64 * 2);
    float* HA = (float*)take((size_t)N * 64 * 4);
    float* HB = (float*)take((size_t)N * 64 * 4);
    (void)ws_size;
    (void)n_in;
    (void)out_size;

    // pairs buffer aliases Yh: CSR build fully precedes gemm0's writes to Yh,
    // and E*4 (6.4MB) <= N*64*2 (12.8MB).
    unsigned* pairs = (unsigned*)Yh;

    int nb = (N + 255) / 256;

    // CSR build (no global atomics)
    hist_k<<<NBLK, 256, 0, stream>>>(dstp, E, nb, ghist);
    col_scan_k<<<nb, 256, 0, stream>>>(ghist, colsum);
    bucket_scan_k<<<1, 512, 0, stream>>>(colsum, bbase, nb);
    partition_k<<<NBLK, 256, 0, stream>>>(src, dstp, ghist, bbase, pairs, E, nb);
    bucket_fill2_k<<<nb, 256, 0, stream>>>(pairs, bbase, colsum, rowptr, adj, N, E);

    float* out = (float*)d_out;
    int gb = (N + 63) / 64;
    int ab = (N + 3) / 4;

    // layer 0: x -> HA (relu)
    gemm_tile_k<64><<<gb, 256, 0, stream>>>(x, Wl0, Wr0, b0, Yh, HA, N);
    aggregate_k<64, true><<<ab, 256, 0, stream>>>(rowptr, adj, Yh, HA, N);
    // layer 1: HA -> HB (relu)
    gemm_tile_k<64><<<gb, 256, 0, stream>>>(HA, Wl1, Wr1, b1, Yh, HB, N);
    aggregate_k<64, true><<<ab, 256, 0, stream>>>(rowptr, adj, Yh, HB, N);
    // layer 2: HB -> out (no relu)
    gemm_tile_k<32><<<gb, 256, 0, stream>>>(HB, Wl2, Wr2, b2, Yh, out, N);
    aggregate_k<32, false><<<ab, 256, 0, stream>>>(rowptr, adj, Yh, out, N);
}

// Round 7
// 227.621 us; speedup vs baseline: 3.9199x; 1.1295x over previous
//
#include <hip/hip_runtime.h>
#include <hip/hip_fp16.h>

// GraphSAGE 3-layer encoder, MI355X.
// Transform-then-aggregate (mean agg is linear), CSR built per-launch
// (atomic-free radix partition, R4). Y stored fp16 (R5).
// R6: aggregate remapped wave=8 nodes (8-lane group per node, lane owns its
// dims end-to-end) -> deletes the 48-op/node shfl reduce. Degree divergence
// across groups accepted (max-of-8 ~ 1.5x mean).

#define MAXB 512   // max node buckets (bucket = 256 nodes); N <= 131072
#define NBLK 256   // partition blocks

// ---- pass 1: per-block histogram over dst buckets ----
__global__ __launch_bounds__(256) void hist_k(const int* __restrict__ dst, int E,
                                              int nb, int* __restrict__ ghist) {
    __shared__ int h[MAXB];
    for (int i = threadIdx.x; i < nb; i += 256) h[i] = 0;
    __syncthreads();
    int chunk = (E + NBLK - 1) / NBLK;
    int e0 = blockIdx.x * chunk, e1 = min(e0 + chunk, E);
    for (int e = e0 + threadIdx.x; e < e1; e += 256) atomicAdd(&h[dst[e] >> 8], 1);
    __syncthreads();
    for (int i = threadIdx.x; i < nb; i += 256) ghist[blockIdx.x * MAXB + i] = h[i];
}

// ---- pass 2a: per-bucket exclusive scan over block counts (in place) ----
__global__ __launch_bounds__(256) void col_scan_k(int* __restrict__ ghist,
                                                  int* __restrict__ colsum) {
    int bucket = blockIdx.x;
    int t = threadIdx.x;
    __shared__ int s[256];
    int v = ghist[t * MAXB + bucket];
    s[t] = v;
    __syncthreads();
    for (int off = 1; off < 256; off <<= 1) {
        int x = (t >= off) ? s[t - off] : 0;
        __syncthreads();
        s[t] += x;
        __syncthreads();
    }
    ghist[t * MAXB + bucket] = s[t] - v;  // exclusive prefix for this block
    if (t == 255) colsum[bucket] = s[255];
}

// ---- pass 2b: exclusive scan of bucket totals ----
__global__ __launch_bounds__(512) void bucket_scan_k(const int* __restrict__ colsum,
                                                     int* __restrict__ bbase, int nb) {
    __shared__ int s[512];
    int t = threadIdx.x;
    int v = (t < nb) ? colsum[t] : 0;
    s[t] = v;
    __syncthreads();
    for (int off = 1; off < 512; off <<= 1) {
        int x = (t >= off) ? s[t - off] : 0;
        __syncthreads();
        s[t] += x;
        __syncthreads();
    }
    if (t < nb) bbase[t] = s[t] - v;
}

// ---- pass 3: scatter edges into private contiguous sub-ranges ----
__global__ __launch_bounds__(256) void partition_k(const int* __restrict__ src,
                                                   const int* __restrict__ dst,
                                                   const int* __restrict__ ghist,
                                                   const int* __restrict__ bbase,
                                                   unsigned* __restrict__ pairs,
                                                   int E, int nb) {
    __shared__ int cur[MAXB];
    for (int i = threadIdx.x; i < nb; i += 256)
        cur[i] = bbase[i] + ghist[blockIdx.x * MAXB + i];
    __syncthreads();
    int chunk = (E + NBLK - 1) / NBLK;
    int e0 = blockIdx.x * chunk, e1 = min(e0 + chunk, E);
    for (int e = e0 + threadIdx.x; e < e1; e += 256) {
        int d = dst[e];
        int b = d >> 8;
        int pos = atomicAdd(&cur[b], 1);               // LDS atomic only
        pairs[pos] = ((unsigned)(d & 255) << 24) | (unsigned)src[e];
    }
}

// ---- pass 4: per-bucket local-deg count + scan -> rowptr; scatter adj ----
__global__ __launch_bounds__(256) void bucket_fill2_k(const unsigned* __restrict__ pairs,
                                                      const int* __restrict__ bbase,
                                                      const int* __restrict__ colsum,
                                                      int* __restrict__ rowptr,
                                                      int* __restrict__ adj,
                                                      int N, int E) {
    int b = blockIdx.x, t = threadIdx.x;
    int node0 = b << 8;
    int nloc = min(256, N - node0);
    int e0 = bbase[b];
    int e1 = e0 + colsum[b];
    __shared__ int cnt[256];
    __shared__ int s[256];
    __shared__ int base[256];
    cnt[t] = 0;
    __syncthreads();
    for (int e = e0 + t; e < e1; e += 256) atomicAdd(&cnt[pairs[e] >> 24], 1);
    __syncthreads();
    int v = cnt[t];
    s[t] = v;
    __syncthreads();
    for (int off = 1; off < 256; off <<= 1) {
        int x = (t >= off) ? s[t - off] : 0;
        __syncthreads();
        s[t] += x;
        __syncthreads();
    }
    base[t] = e0 + s[t] - v;  // exclusive
    if (t < nloc) rowptr[node0 + t] = base[t];
    if (b == 0 && t == 0) rowptr[N] = E;
    cnt[t] = 0;
    __syncthreads();
    for (int e = e0 + t; e < e1; e += 256) {
        unsigned p = pairs[e];
        int l = p >> 24;
        int pos = base[l] + atomicAdd(&cnt[l], 1);     // LDS atomic only
        adj[pos] = (int)(p & 0xFFFFFFu);
    }
}

// ---------------- tiled dual GEMM: Y(fp16) = H @ Wl^T ; Z(fp32) = H @ Wr^T + b ----------------

template <int DOUT>
__global__ __launch_bounds__(256, 2) void gemm_tile_k(const float* __restrict__ H,
                                                      const float* __restrict__ Wl,
                                                      const float* __restrict__ Wr,
                                                      const float* __restrict__ b,
                                                      __half* __restrict__ Y,
                                                      float* __restrict__ Z, int N) {
    constexpr int DOUT2 = 2 * DOUT;   // 128 or 64
    constexpr int CPT = DOUT2 / 16;   // cols/thread: 8 or 4
    constexpr int ST = 68;            // padded LDS stride (floats)
    __shared__ float hs[64 * ST];
    __shared__ float ws[DOUT2 * ST];
    int t = threadIdx.x;

    for (int i = t; i < DOUT2 * 16; i += 256) {
        int c = i >> 4, j4 = i & 15;
        float4 w = (c < DOUT) ? reinterpret_cast<const float4*>(Wl)[c * 16 + j4]
                              : reinterpret_cast<const float4*>(Wr)[(c - DOUT) * 16 + j4];
        *reinterpret_cast<float4*>(&ws[c * ST + j4 * 4]) = w;
    }
    {
        const float4* H4 = reinterpret_cast<const float4*>(H);
        long base4 = (long)blockIdx.x * 64 * 16;
        long max4 = (long)N * 16 - 1;
        for (int i = t; i < 64 * 16; i += 256) {
            long g = base4 + i;
            if (g > max4) g = max4;
            float4 h = H4[g];
            int row = i >> 4, j4 = i & 15;
            *reinterpret_cast<float4*>(&hs[row * ST + j4 * 4]) = h;
        }
    }
    __syncthreads();

    int tx = t & 15;
    int ty = t >> 4;
    float acc[4][CPT];
#pragma unroll
    for (int r = 0; r < 4; r++)
#pragma unroll
        for (int c = 0; c < CPT; c++) acc[r][c] = 0.f;

#pragma unroll 2
    for (int k4 = 0; k4 < 16; ++k4) {
        float4 a[4], w[CPT];
#pragma unroll
        for (int r = 0; r < 4; r++)
            a[r] = *reinterpret_cast<const float4*>(&hs[(ty * 4 + r) * ST + k4 * 4]);
#pragma unroll
        for (int c = 0; c < CPT; c++)
            w[c] = *reinterpret_cast<const float4*>(&ws[(tx + 16 * c) * ST + k4 * 4]);
#pragma unroll
        for (int r = 0; r < 4; r++)
#pragma unroll
            for (int c = 0; c < CPT; c++)
                acc[r][c] = fmaf(a[r].x, w[c].x,
                            fmaf(a[r].y, w[c].y,
                            fmaf(a[r].z, w[c].z, fmaf(a[r].w, w[c].w, acc[r][c]))));
    }

    int row0 = blockIdx.x * 64 + ty * 4;
#pragma unroll
    for (int r = 0; r < 4; r++) {
        int row = row0 + r;
        if (row >= N) break;
#pragma unroll
        for (int c = 0; c < CPT; c++) {
            int col = tx + 16 * c;
            if (col < DOUT)
                Y[(long)row * DOUT + col] = __float2half(acc[r][c]);
            else
                Z[(long)row * DOUT + (col - DOUT)] = acc[r][c] + b[col - DOUT];
        }
    }
}

// ---------------- aggregate: H[i] += mean_{e in adj(i)} Y[adj[e]] ; opt ReLU ----------------
// Y is fp16. FPR lanes form a group owning one node; lane d8 owns 8 dims
// end-to-end (no cross-lane reduce). NPW nodes per wave.

template <int DOUT, bool RELU>
__global__ __launch_bounds__(256) void aggregate_k(const int* __restrict__ rp,
                                                   const int* __restrict__ adj,
                                                   const __half* __restrict__ Yh,
                                                   float* __restrict__ H, int N) {
    constexpr int FPR = DOUT / 8;        // lanes per node: 8 (d64) or 4 (d32)
    constexpr int NPW = 64 / FPR;        // nodes per wave: 8 or 16
    int wave = threadIdx.x >> 6;
    int lane = threadIdx.x & 63;
    int g = lane / FPR;
    int d8 = lane % FPR;
    int node = (blockIdx.x * 4 + wave) * NPW + g;
    if (node >= N) return;
    int s0 = rp[node], s1 = rp[node + 1];
    const float4* Y4 = reinterpret_cast<const float4*>(Yh);
    float acc[8];
#pragma unroll
    for (int k = 0; k < 8; k++) acc[k] = 0.f;

    int e = s0;
    for (; e + 2 <= s1; e += 2) {
        int a0 = adj[e], a1 = adj[e + 1];
        float4 r0 = Y4[(unsigned)a0 * FPR + d8];
        float4 r1 = Y4[(unsigned)a1 * FPR + d8];
        const __half2* h0 = reinterpret_cast<const __half2*>(&r0);
        const __half2* h1 = reinterpret_cast<const __half2*>(&r1);
#pragma unroll
        for (int k = 0; k < 4; k++) {
            float2 f0 = __half22float2(h0[k]);
            float2 f1 = __half22float2(h1[k]);
            acc[2 * k] += f0.x + f1.x;
            acc[2 * k + 1] += f0.y + f1.y;
        }
    }
    if (e < s1) {
        float4 r0 = Y4[(unsigned)adj[e] * FPR + d8];
        const __half2* h0 = reinterpret_cast<const __half2*>(&r0);
#pragma unroll
        for (int k = 0; k < 4; k++) {
            float2 f0 = __half22float2(h0[k]);
            acc[2 * k] += f0.x;
            acc[2 * k + 1] += f0.y;
        }
    }
    int deg = s1 - s0;
    float inv = (deg > 0) ? 1.f / (float)deg : 0.f;
    float4* H4 = reinterpret_cast<float4*>(H);
    long hb = (long)node * (DOUT / 4) + d8 * 2;  // lane owns 8 consecutive dims
    float4 v0 = H4[hb], v1 = H4[hb + 1];
    v0.x += acc[0] * inv; v0.y += acc[1] * inv;
    v0.z += acc[2] * inv; v0.w += acc[3] * inv;
    v1.x += acc[4] * inv; v1.y += acc[5] * inv;
    v1.z += acc[6] * inv; v1.w += acc[7] * inv;
    if (RELU) {
        v0.x = fmaxf(v0.x, 0.f); v0.y = fmaxf(v0.y, 0.f);
        v0.z = fmaxf(v0.z, 0.f); v0.w = fmaxf(v0.w, 0.f);
        v1.x = fmaxf(v1.x, 0.f); v1.y = fmaxf(v1.y, 0.f);
        v1.z = fmaxf(v1.z, 0.f); v1.w = fmaxf(v1.w, 0.f);
    }
    H4[hb] = v0;
    H4[hb + 1] = v1;
}

// ---------------- launch ----------------

extern "C" void kernel_launch(void* const* d_in, const int* in_sizes, int n_in,
                              void* d_out, int out_size, void* d_ws, size_t ws_size,
                              hipStream_t stream) {
    const float* x = (const float*)d_in[0];
    const int* ei = (const int*)d_in[1];  // int32
    const float* Wl0 = (const float*)d_in[3];
    const float* Wr0 = (const float*)d_in[4];
    const float* b0 = (const float*)d_in[5];
    const float* Wl1 = (const float*)d_in[6];
    const float* Wr1 = (const float*)d_in[7];
    const float* b1 = (const float*)d_in[8];
    const float* Wl2 = (const float*)d_in[9];
    const float* Wr2 = (const float*)d_in[10];
    const float* b2 = (const float*)d_in[11];

    int N = in_sizes[0] / 64;
    int E = in_sizes[1] / 2;
    const int* src = ei;
    const int* dstp = ei + E;

    char* ws = (char*)d_ws;
    size_t off = 0;
    auto take = [&](size_t bytes) -> void* {
        void* p = ws + off;
        off = (off + bytes + 255) & ~(size_t)255;
        return p;
    };
    int* rowptr = (int*)take((size_t)(N + 1) * 4);
    int* ghist = (int*)take((size_t)NBLK * MAXB * 4);
    int* colsum = (int*)take(MAXB * 4);
    int* bbase = (int*)take(MAXB * 4);
    int* adj = (int*)take((size_t)E * 4);
    __half* Yh = (__half*)take((size_t)N * 64 * 2);
    float* HA = (float*)take((size_t)N * 64 * 4);
    float* HB = (float*)take((size_t)N * 64 * 4);
    (void)ws_size;
    (void)n_in;
    (void)out_size;

    // pairs buffer aliases Yh: CSR build fully precedes gemm0's writes to Yh,
    // and E*4 (6.4MB) <= N*64*2 (12.8MB).
    unsigned* pairs = (unsigned*)Yh;

    int nb = (N + 255) / 256;

    // CSR build (no global atomics)
    hist_k<<<NBLK, 256, 0, stream>>>(dstp, E, nb, ghist);
    col_scan_k<<<nb, 256, 0, stream>>>(ghist, colsum);
    bucket_scan_k<<<1, 512, 0, stream>>>(colsum, bbase, nb);
    partition_k<<<NBLK, 256, 0, stream>>>(src, dstp, ghist, bbase, pairs, E, nb);
    bucket_fill2_k<<<nb, 256, 0, stream>>>(pairs, bbase, colsum, rowptr, adj, N, E);

    float* out = (float*)d_out;
    int gb = (N + 63) / 64;
    int ab64 = (N + 31) / 32;    // 4 waves x 8 nodes
    int ab32 = (N + 63) / 64;    // 4 waves x 16 nodes

    // layer 0: x -> HA (relu)
    gemm_tile_k<64><<<gb, 256, 0, stream>>>(x, Wl0, Wr0, b0, Yh, HA, N);
    aggregate_k<64, true><<<ab64, 256, 0, stream>>>(rowptr, adj, Yh, HA, N);
    // layer 1: HA -> HB (relu)
    gemm_tile_k<64><<<gb, 256, 0, stream>>>(HA, Wl1, Wr1, b1, Yh, HB, N);
    aggregate_k<64, true><<<ab64, 256, 0, stream>>>(rowptr, adj, Yh, HB, N);
    // layer 2: HB -> out (no relu)
    gemm_tile_k<32><<<gb, 256, 0, stream>>>(HB, Wl2, Wr2, b2, Yh, out, N);
    aggregate_k<32, false><<<ab32, 256, 0, stream>>>(rowptr, adj, Yh, out, N);
}

// Round 8
// 220.253 us; speedup vs baseline: 4.0510x; 1.0335x over previous
//
#include <hip/hip_runtime.h>
#include <hip/hip_fp16.h>

// GraphSAGE 3-layer encoder, MI355X.
// Transform-then-aggregate (mean agg is linear), CSR built per-launch
// (atomic-free radix partition, R4). Y stored fp16 (R5). Group-per-node
// aggregate, no shuffle reduce (R6).
// R7: gather unroll x4 (4 independent 16B loads in flight -> latency hiding);
// CSR hist/partition at NBLK=512 (2 blocks/CU).

#define MAXB 512   // max node buckets (bucket = 256 nodes); N <= 131072
#define NBLK 512   // partition blocks (2 per CU)

// ---- pass 1: per-block histogram over dst buckets ----
__global__ __launch_bounds__(256) void hist_k(const int* __restrict__ dst, int E,
                                              int nb, int* __restrict__ ghist) {
    __shared__ int h[MAXB];
    for (int i = threadIdx.x; i < nb; i += 256) h[i] = 0;
    __syncthreads();
    int chunk = (E + NBLK - 1) / NBLK;
    int e0 = blockIdx.x * chunk, e1 = min(e0 + chunk, E);
    for (int e = e0 + threadIdx.x; e < e1; e += 256) atomicAdd(&h[dst[e] >> 8], 1);
    __syncthreads();
    for (int i = threadIdx.x; i < nb; i += 256) ghist[blockIdx.x * MAXB + i] = h[i];
}

// ---- pass 2a: per-bucket exclusive scan over NBLK block counts (in place) ----
__global__ __launch_bounds__(512) void col_scan_k(int* __restrict__ ghist,
                                                  int* __restrict__ colsum) {
    int bucket = blockIdx.x;
    int t = threadIdx.x;
    __shared__ int s[NBLK];
    int v = ghist[t * MAXB + bucket];
    s[t] = v;
    __syncthreads();
    for (int off = 1; off < NBLK; off <<= 1) {
        int x = (t >= off) ? s[t - off] : 0;
        __syncthreads();
        s[t] += x;
        __syncthreads();
    }
    ghist[t * MAXB + bucket] = s[t] - v;  // exclusive prefix for this block
    if (t == NBLK - 1) colsum[bucket] = s[NBLK - 1];
}

// ---- pass 2b: exclusive scan of bucket totals ----
__global__ __launch_bounds__(512) void bucket_scan_k(const int* __restrict__ colsum,
                                                     int* __restrict__ bbase, int nb) {
    __shared__ int s[512];
    int t = threadIdx.x;
    int v = (t < nb) ? colsum[t] : 0;
    s[t] = v;
    __syncthreads();
    for (int off = 1; off < 512; off <<= 1) {
        int x = (t >= off) ? s[t - off] : 0;
        __syncthreads();
        s[t] += x;
        __syncthreads();
    }
    if (t < nb) bbase[t] = s[t] - v;
}

// ---- pass 3: scatter edges into private contiguous sub-ranges ----
__global__ __launch_bounds__(256) void partition_k(const int* __restrict__ src,
                                                   const int* __restrict__ dst,
                                                   const int* __restrict__ ghist,
                                                   const int* __restrict__ bbase,
                                                   unsigned* __restrict__ pairs,
                                                   int E, int nb) {
    __shared__ int cur[MAXB];
    for (int i = threadIdx.x; i < nb; i += 256)
        cur[i] = bbase[i] + ghist[blockIdx.x * MAXB + i];
    __syncthreads();
    int chunk = (E + NBLK - 1) / NBLK;
    int e0 = blockIdx.x * chunk, e1 = min(e0 + chunk, E);
    for (int e = e0 + threadIdx.x; e < e1; e += 256) {
        int d = dst[e];
        int b = d >> 8;
        int pos = atomicAdd(&cur[b], 1);               // LDS atomic only
        pairs[pos] = ((unsigned)(d & 255) << 24) | (unsigned)src[e];
    }
}

// ---- pass 4: per-bucket local-deg count + scan -> rowptr; scatter adj ----
__global__ __launch_bounds__(256) void bucket_fill2_k(const unsigned* __restrict__ pairs,
                                                      const int* __restrict__ bbase,
                                                      const int* __restrict__ colsum,
                                                      int* __restrict__ rowptr,
                                                      int* __restrict__ adj,
                                                      int N, int E) {
    int b = blockIdx.x, t = threadIdx.x;
    int node0 = b << 8;
    int nloc = min(256, N - node0);
    int e0 = bbase[b];
    int e1 = e0 + colsum[b];
    __shared__ int cnt[256];
    __shared__ int s[256];
    __shared__ int base[256];
    cnt[t] = 0;
    __syncthreads();
    for (int e = e0 + t; e < e1; e += 256) atomicAdd(&cnt[pairs[e] >> 24], 1);
    __syncthreads();
    int v = cnt[t];
    s[t] = v;
    __syncthreads();
    for (int off = 1; off < 256; off <<= 1) {
        int x = (t >= off) ? s[t - off] : 0;
        __syncthreads();
        s[t] += x;
        __syncthreads();
    }
    base[t] = e0 + s[t] - v;  // exclusive
    if (t < nloc) rowptr[node0 + t] = base[t];
    if (b == 0 && t == 0) rowptr[N] = E;
    cnt[t] = 0;
    __syncthreads();
    for (int e = e0 + t; e < e1; e += 256) {
        unsigned p = pairs[e];
        int l = p >> 24;
        int pos = base[l] + atomicAdd(&cnt[l], 1);     // LDS atomic only
        adj[pos] = (int)(p & 0xFFFFFFu);
    }
}

// ---------------- tiled dual GEMM: Y(fp16) = H @ Wl^T ; Z(fp32) = H @ Wr^T + b ----------------

template <int DOUT>
__global__ __launch_bounds__(256, 2) void gemm_tile_k(const float* __restrict__ H,
                                                      const float* __restrict__ Wl,
                                                      const float* __restrict__ Wr,
                                                      const float* __restrict__ b,
                                                      __half* __restrict__ Y,
                                                      float* __restrict__ Z, int N) {
    constexpr int DOUT2 = 2 * DOUT;   // 128 or 64
    constexpr int CPT = DOUT2 / 16;   // cols/thread: 8 or 4
    constexpr int ST = 68;            // padded LDS stride (floats)
    __shared__ float hs[64 * ST];
    __shared__ float ws[DOUT2 * ST];
    int t = threadIdx.x;

    for (int i = t; i < DOUT2 * 16; i += 256) {
        int c = i >> 4, j4 = i & 15;
        float4 w = (c < DOUT) ? reinterpret_cast<const float4*>(Wl)[c * 16 + j4]
                              : reinterpret_cast<const float4*>(Wr)[(c - DOUT) * 16 + j4];
        *reinterpret_cast<float4*>(&ws[c * ST + j4 * 4]) = w;
    }
    {
        const float4* H4 = reinterpret_cast<const float4*>(H);
        long base4 = (long)blockIdx.x * 64 * 16;
        long max4 = (long)N * 16 - 1;
        for (int i = t; i < 64 * 16; i += 256) {
            long g = base4 + i;
            if (g > max4) g = max4;
            float4 h = H4[g];
            int row = i >> 4, j4 = i & 15;
            *reinterpret_cast<float4*>(&hs[row * ST + j4 * 4]) = h;
        }
    }
    __syncthreads();

    int tx = t & 15;
    int ty = t >> 4;
    float acc[4][CPT];
#pragma unroll
    for (int r = 0; r < 4; r++)
#pragma unroll
        for (int c = 0; c < CPT; c++) acc[r][c] = 0.f;

#pragma unroll 2
    for (int k4 = 0; k4 < 16; ++k4) {
        float4 a[4], w[CPT];
#pragma unroll
        for (int r = 0; r < 4; r++)
            a[r] = *reinterpret_cast<const float4*>(&hs[(ty * 4 + r) * ST + k4 * 4]);
#pragma unroll
        for (int c = 0; c < CPT; c++)
            w[c] = *reinterpret_cast<const float4*>(&ws[(tx + 16 * c) * ST + k4 * 4]);
#pragma unroll
        for (int r = 0; r < 4; r++)
#pragma unroll
            for (int c = 0; c < CPT; c++)
                acc[r][c] = fmaf(a[r].x, w[c].x,
                            fmaf(a[r].y, w[c].y,
                            fmaf(a[r].z, w[c].z, fmaf(a[r].w, w[c].w, acc[r][c]))));
    }

    int row0 = blockIdx.x * 64 + ty * 4;
#pragma unroll
    for (int r = 0; r < 4; r++) {
        int row = row0 + r;
        if (row >= N) break;
#pragma unroll
        for (int c = 0; c < CPT; c++) {
            int col = tx + 16 * c;
            if (col < DOUT)
                Y[(long)row * DOUT + col] = __float2half(acc[r][c]);
            else
                Z[(long)row * DOUT + (col - DOUT)] = acc[r][c] + b[col - DOUT];
        }
    }
}

// ---------------- aggregate: H[i] += mean_{e in adj(i)} Y[adj[e]] ; opt ReLU ----------------
// Y is fp16. FPR lanes form a group owning one node; lane d8 owns 8 dims
// end-to-end (no cross-lane reduce). Gather unrolled x4 for MLP.

template <int DOUT, bool RELU>
__global__ __launch_bounds__(256) void aggregate_k(const int* __restrict__ rp,
                                                   const int* __restrict__ adj,
                                                   const __half* __restrict__ Yh,
                                                   float* __restrict__ H, int N) {
    constexpr int FPR = DOUT / 8;        // lanes per node: 8 (d64) or 4 (d32)
    constexpr int NPW = 64 / FPR;        // nodes per wave: 8 or 16
    int wave = threadIdx.x >> 6;
    int lane = threadIdx.x & 63;
    int g = lane / FPR;
    int d8 = lane % FPR;
    int node = (blockIdx.x * 4 + wave) * NPW + g;
    if (node >= N) return;
    int s0 = rp[node], s1 = rp[node + 1];
    const float4* Y4 = reinterpret_cast<const float4*>(Yh);
    float acc[8];
#pragma unroll
    for (int k = 0; k < 8; k++) acc[k] = 0.f;

    int e = s0;
    for (; e + 4 <= s1; e += 4) {
        int a0 = adj[e], a1 = adj[e + 1], a2 = adj[e + 2], a3 = adj[e + 3];
        float4 r0 = Y4[(unsigned)a0 * FPR + d8];
        float4 r1 = Y4[(unsigned)a1 * FPR + d8];
        float4 r2 = Y4[(unsigned)a2 * FPR + d8];
        float4 r3 = Y4[(unsigned)a3 * FPR + d8];
        const __half2* h0 = reinterpret_cast<const __half2*>(&r0);
        const __half2* h1 = reinterpret_cast<const __half2*>(&r1);
        const __half2* h2 = reinterpret_cast<const __half2*>(&r2);
        const __half2* h3 = reinterpret_cast<const __half2*>(&r3);
#pragma unroll
        for (int k = 0; k < 4; k++) {
            float2 f0 = __half22float2(h0[k]);
            float2 f1 = __half22float2(h1[k]);
            float2 f2 = __half22float2(h2[k]);
            float2 f3 = __half22float2(h3[k]);
            acc[2 * k]     += (f0.x + f1.x) + (f2.x + f3.x);
            acc[2 * k + 1] += (f0.y + f1.y) + (f2.y + f3.y);
        }
    }
    for (; e < s1; e++) {
        float4 r0 = Y4[(unsigned)adj[e] * FPR + d8];
        const __half2* h0 = reinterpret_cast<const __half2*>(&r0);
#pragma unroll
        for (int k = 0; k < 4; k++) {
            float2 f0 = __half22float2(h0[k]);
            acc[2 * k] += f0.x;
            acc[2 * k + 1] += f0.y;
        }
    }
    int deg = s1 - s0;
    float inv = (deg > 0) ? 1.f / (float)deg : 0.f;
    float4* H4 = reinterpret_cast<float4*>(H);
    long hb = (long)node * (DOUT / 4) + d8 * 2;  // lane owns 8 consecutive dims
    float4 v0 = H4[hb], v1 = H4[hb + 1];
    v0.x += acc[0] * inv; v0.y += acc[1] * inv;
    v0.z += acc[2] * inv; v0.w += acc[3] * inv;
    v1.x += acc[4] * inv; v1.y += acc[5] * inv;
    v1.z += acc[6] * inv; v1.w += acc[7] * inv;
    if (RELU) {
        v0.x = fmaxf(v0.x, 0.f); v0.y = fmaxf(v0.y, 0.f);
        v0.z = fmaxf(v0.z, 0.f); v0.w = fmaxf(v0.w, 0.f);
        v1.x = fmaxf(v1.x, 0.f); v1.y = fmaxf(v1.y, 0.f);
        v1.z = fmaxf(v1.z, 0.f); v1.w = fmaxf(v1.w, 0.f);
    }
    H4[hb] = v0;
    H4[hb + 1] = v1;
}

// ---------------- launch ----------------

extern "C" void kernel_launch(void* const* d_in, const int* in_sizes, int n_in,
                              void* d_out, int out_size, void* d_ws, size_t ws_size,
                              hipStream_t stream) {
    const float* x = (const float*)d_in[0];
    const int* ei = (const int*)d_in[1];  // int32
    const float* Wl0 = (const float*)d_in[3];
    const float* Wr0 = (const float*)d_in[4];
    const float* b0 = (const float*)d_in[5];
    const float* Wl1 = (const float*)d_in[6];
    const float* Wr1 = (const float*)d_in[7];
    const float* b1 = (const float*)d_in[8];
    const float* Wl2 = (const float*)d_in[9];
    const float* Wr2 = (const float*)d_in[10];
    const float* b2 = (const float*)d_in[11];

    int N = in_sizes[0] / 64;
    int E = in_sizes[1] / 2;
    const int* src = ei;
    const int* dstp = ei + E;

    char* ws = (char*)d_ws;
    size_t off = 0;
    auto take = [&](size_t bytes) -> void* {
        void* p = ws + off;
        off = (off + bytes + 255) & ~(size_t)255;
        return p;
    };
    int* rowptr = (int*)take((size_t)(N + 1) * 4);
    int* ghist = (int*)take((size_t)NBLK * MAXB * 4);
    int* colsum = (int*)take(MAXB * 4);
    int* bbase = (int*)take(MAXB * 4);
    int* adj = (int*)take((size_t)E * 4);
    __half* Yh = (__half*)take((size_t)N * 64 * 2);
    float* HA = (float*)take((size_t)N * 64 * 4);
    float* HB = (float*)take((size_t)N * 64 * 4);
    (void)ws_size;
    (void)n_in;
    (void)out_size;

    // pairs buffer aliases Yh: CSR build fully precedes gemm0's writes to Yh,
    // and E*4 (6.4MB) <= N*64*2 (12.8MB).
    unsigned* pairs = (unsigned*)Yh;

    int nb = (N + 255) / 256;

    // CSR build (no global atomics)
    hist_k<<<NBLK, 256, 0, stream>>>(dstp, E, nb, ghist);
    col_scan_k<<<nb, 512, 0, stream>>>(ghist, colsum);
    bucket_scan_k<<<1, 512, 0, stream>>>(colsum, bbase, nb);
    partition_k<<<NBLK, 256, 0, stream>>>(src, dstp, ghist, bbase, pairs, E, nb);
    bucket_fill2_k<<<nb, 256, 0, stream>>>(pairs, bbase, colsum, rowptr, adj, N, E);

    float* out = (float*)d_out;
    int gb = (N + 63) / 64;
    int ab64 = (N + 31) / 32;    // 4 waves x 8 nodes
    int ab32 = (N + 63) / 64;    // 4 waves x 16 nodes

    // layer 0: x -> HA (relu)
    gemm_tile_k<64><<<gb, 256, 0, stream>>>(x, Wl0, Wr0, b0, Yh, HA, N);
    aggregate_k<64, true><<<ab64, 256, 0, stream>>>(rowptr, adj, Yh, HA, N);
    // layer 1: HA -> HB (relu)
    gemm_tile_k<64><<<gb, 256, 0, stream>>>(HA, Wl1, Wr1, b1, Yh, HB, N);
    aggregate_k<64, true><<<ab64, 256, 0, stream>>>(rowptr, adj, Yh, HB, N);
    // layer 2: HB -> out (no relu)
    gemm_tile_k<32><<<gb, 256, 0, stream>>>(HB, Wl2, Wr2, b2, Yh, out, N);
    aggregate_k<32, false><<<ab32, 256, 0, stream>>>(rowptr, adj, Yh, out, N);
}